// Round 3
// baseline (2440.404 us; speedup 1.0000x reference)
//
#include <hip/hip_runtime.h>

typedef unsigned short u16;
typedef unsigned int   u32;

#define BT 8
#define TX 30
#define TY 10

__device__ __forceinline__ float lo2f(u32 p){ u32 i=p<<16; float f; __builtin_memcpy(&f,&i,4); return f; }
__device__ __forceinline__ float hi2f(u32 p){ u32 i=p&0xffff0000u; float f; __builtin_memcpy(&f,&i,4); return f; }
__device__ __forceinline__ u16 f2bf(float f){ u32 x; __builtin_memcpy(&x,&f,4); u32 r=(x+0x7fffu+((x>>16)&1u))>>16; return (u16)r; }
__device__ __forceinline__ u32 pack2(float a, float b){ return (u32)f2bf(a) | ((u32)f2bf(b)<<16); }
__device__ __forceinline__ float sigm(float x){ return 1.0f/(1.0f+__expf(-x)); }
__device__ __forceinline__ float tanh_(float x){ x=fminf(fmaxf(x,-15.0f),15.0f); float e=__expf(2.0f*x); return (e-1.0f)/(e+1.0f); }

struct SmemEnc {
    float x[2][BT][132];   // staged x_t (fwd t / rev 29-t), fp32, stride 132 (33 float4)
    float h[2][BT][36];    // recurrent h, fp32
    float z[2][BT][128];   // gate pre-activations
};
struct SmemDec {
    float w1f[10][128];    // W1 fp32
    u16   wof16[64][64];   // Wo transposed [k][j], bf16
    float z2[BT][256];     // post-cell pre-activations
    float s[BT][68];       // decoder state s (stride 68 = 17 float4)
    float ctx[BT][68];     // context
    float sW1[BT][12];     // b1 + s @ W1[:,64:].T
    float en[BT][32];
    float alpha[BT][32];
    float rowm[BT], rowinv[BT];
    float b1f[12], w2f[12], bof[64];
    float b2s;
};
union SmemU { SmemEnc e; SmemDec d; };
struct Smem {
    u16 a[BT][TX][66];     // encoder outputs, bf16, stride 66 breaks pow2 banks
    SmemU u;
};

__global__ __launch_bounds__(256, 2) void fused_kernel(
    const float* __restrict__ X,
    const float* __restrict__ Wihf, const float* __restrict__ Whhf, const float* __restrict__ bfv,
    const float* __restrict__ Wihr, const float* __restrict__ Whhr, const float* __restrict__ brv,
    const float* __restrict__ W1, const float* __restrict__ b1, const float* __restrict__ W2, const float* __restrict__ b2,
    const float* __restrict__ Wihp, const float* __restrict__ Whhp, const float* __restrict__ bp,
    const float* __restrict__ Wo, const float* __restrict__ bo,
    float* __restrict__ out)
{
    __shared__ __align__(16) Smem sm;
    const int tid = threadIdx.x;
    const int b0  = blockIdx.x * BT;

    // zero ALL of LDS: any read of a not-yet-written word yields 0.0, never stale garbage
    {
        u32* p = (u32*)&sm;
        const int nw = (int)(sizeof(Smem) / 4);
        for (int i = tid; i < nw; i += 256) p[i] = 0u;
    }
    __syncthreads();

    // ===================== encoder =====================
    const int ed = tid >> 7;      // direction: 0 fwd, 1 rev
    const int ej = tid & 127;     // gate row (PyTorch order i,f,g,o as chunks of 32)
    const float* Wih = ed ? Wihr : Wihf;
    const float* Whh = ed ? Whhr : Whhf;

    u32 wih[64], whh[16];         // fp32 weights rounded to packed bf16 in registers
    {
        const float2* p = (const float2*)(Wih + ej*128);
        #pragma unroll
        for (int i=0;i<64;i++){ float2 v=p[i]; wih[i]=pack2(v.x,v.y); }
        const float2* q = (const float2*)(Whh + ej*32);
        #pragma unroll
        for (int i=0;i<16;i++){ float2 v=q[i]; whh[i]=pack2(v.x,v.y); }
    }
    const float ebias = (ed ? brv : bfv)[ej];

    const int gr = tid >> 5;      // gate-update mapping: row
    const int gu = tid & 31;      // unit
    float c_f = 0.f, c_r = 0.f;

    for (int t = 0; t < TX; t++) {
        {   // stage x for both directions (fp32 straight copy, 2 x float4 per thread)
            const int sd = tid >> 7, sr = (tid >> 4) & 7, sk = tid & 15;
            const int tsrc = sd ? (TX-1-t) : t;
            const float4* src = (const float4*)(X + (((long)(b0+sr))*TX + tsrc)*128) + sk*2;
            const float4 v0 = src[0], v1 = src[1];
            *(float4*)&sm.u.e.x[sd][sr][sk*8]     = v0;
            *(float4*)&sm.u.e.x[sd][sr][sk*8 + 4] = v1;
        }
        __syncthreads();

        float acc[BT];
        #pragma unroll
        for (int r=0;r<BT;r++) acc[r] = ebias;

        const float4* x4 = (const float4*)&sm.u.e.x[ed][0][0];
        #pragma unroll
        for (int k4=0;k4<32;k4++){
            const u32 p0 = wih[2*k4], p1 = wih[2*k4+1];
            const float w0=lo2f(p0), w1=hi2f(p0), w2v=lo2f(p1), w3=hi2f(p1);
            #pragma unroll
            for (int r=0;r<BT;r++){
                const float4 xv = x4[r*33 + k4];       // broadcast read
                acc[r] += xv.x*w0 + xv.y*w1 + xv.z*w2v + xv.w*w3;
            }
        }
        const float4* h4 = (const float4*)&sm.u.e.h[ed][0][0];
        #pragma unroll
        for (int k4=0;k4<8;k4++){
            const u32 p0 = whh[2*k4], p1 = whh[2*k4+1];
            const float w0=lo2f(p0), w1=hi2f(p0), w2v=lo2f(p1), w3=hi2f(p1);
            #pragma unroll
            for (int r=0;r<BT;r++){
                const float4 hv = h4[r*9 + k4];
                acc[r] += hv.x*w0 + hv.y*w1 + hv.z*w2v + hv.w*w3;
            }
        }
        #pragma unroll
        for (int r=0;r<BT;r++) sm.u.e.z[ed][r][ej] = acc[r];
        __syncthreads();

        {   // gate update: each thread owns unit (gr,gu) in BOTH directions
            const float* z0 = sm.u.e.z[0][gr];
            float i0=sigm(z0[gu]), f0=sigm(z0[gu+32]), g0=tanh_(z0[gu+64]), o0=sigm(z0[gu+96]);
            c_f = f0*c_f + i0*g0;
            const float h0 = o0*tanh_(c_f);
            sm.u.e.h[0][gr][gu] = h0;
            sm.a[gr][t][gu] = f2bf(h0);

            const float* z1 = sm.u.e.z[1][gr];
            float i1=sigm(z1[gu]), f1=sigm(z1[gu+32]), g1=tanh_(z1[gu+64]), o1=sigm(z1[gu+96]);
            c_r = f1*c_r + i1*g1;
            const float h1 = o1*tanh_(c_r);
            sm.u.e.h[1][gr][gu] = h1;
            sm.a[gr][TX-1-t][32+gu] = f2bf(h1);   // reversed-output placement
        }
        __syncthreads();
    }

    // ===================== decoder =====================
    // stage shared decoder data (aliases encoder smem; encoder done + synced)
    for (int i=tid;i<1280;i+=256) ((float*)sm.u.d.w1f)[i] = W1[i];     // [10][128], stride matches
    for (int i=tid;i<4096;i+=256){ int jj=i>>6, kk=i&63; sm.u.d.wof16[kk][jj] = f2bf(Wo[i]); }
    for (int i=tid;i<BT*68;i+=256) ((float*)sm.u.d.s)[i] = 0.f;
    if (tid < 64) sm.u.d.bof[tid] = bo[tid];
    if (tid < 10){ sm.u.d.b1f[tid] = b1[tid]; sm.u.d.w2f[tid] = W2[tid]; }
    if (tid == 0) sm.u.d.b2s = b2[0];
    __syncthreads();

    // per-thread post-cell weights (gate j2 = tid), fp32 -> packed bf16 in registers
    u32 wip[32], whp[32];
    {
        const float2* p = (const float2*)(Wihp + tid*64);
        #pragma unroll
        for (int i=0;i<32;i++){ float2 v=p[i]; wip[i]=pack2(v.x,v.y); }
        const float2* q = (const float2*)(Whhp + tid*64);
        #pragma unroll
        for (int i=0;i<32;i++){ float2 v=q[i]; whp[i]=pack2(v.x,v.y); }
    }
    const float pbias = bp[tid];

    const int er = tid/30, et = tid - er*30;   // e-phase mapping (tid<240)
    const int cr = tid>>5, cup = tid&31;       // ctx mapping
    const int g2r = tid>>6, g2u = tid&63;      // cell-gate & out mapping (rows g2r, g2r+4)
    float c2a = 0.f, c2b = 0.f;

    for (int ty=0; ty<TY; ty++){
        __syncthreads();
        // 1: sW1[r][j1] = b1[j1] + s[r] . W1[j1][64:]
        if (tid < 80){
            const int r = tid/10, j1 = tid - r*10;
            float a = sm.u.d.b1f[j1];
            const float* srow = sm.u.d.s[r];
            const float* wrow = &sm.u.d.w1f[j1][64];
            #pragma unroll 8
            for (int k=0;k<64;k++) a += srow[k]*wrow[k];
            sm.u.d.sW1[r][j1] = a;
        }
        __syncthreads();
        // 2: e = tanh(a-part + sW1); en = relu(e . w2 + b2)
        if (tid < 240){
            float accj[10];
            #pragma unroll
            for (int j1=0;j1<10;j1++) accj[j1] = sm.u.d.sW1[er][j1];
            const u32* arow = (const u32*)&sm.a[er][et][0];
            #pragma unroll 4
            for (int kk=0;kk<32;kk++){
                const u32 pa = arow[kk];
                const float a0 = lo2f(pa), a1 = hi2f(pa);
                #pragma unroll
                for (int j1=0;j1<10;j1++){
                    const float2 wv = *(const float2*)&sm.u.d.w1f[j1][2*kk];
                    accj[j1] += a0*wv.x + a1*wv.y;
                }
            }
            float env = sm.u.d.b2s;
            #pragma unroll
            for (int j1=0;j1<10;j1++) env += sm.u.d.w2f[j1]*tanh_(accj[j1]);
            sm.u.d.en[er][et] = fmaxf(env, 0.f);
        }
        __syncthreads();
        // 3a: per-row softmax max & sum
        if (tid < BT){
            const float* enr = sm.u.d.en[tid];
            float m = enr[0];
            for (int t=1;t<TX;t++) m = fmaxf(m, enr[t]);
            float ssum = 0.f;
            for (int t=0;t<TX;t++) ssum += __expf(enr[t]-m);
            sm.u.d.rowm[tid] = m;
            sm.u.d.rowinv[tid] = 1.0f/ssum;
        }
        __syncthreads();
        // 3b: alphas
        if (tid < 240)
            sm.u.d.alpha[er][et] = __expf(sm.u.d.en[er][et]-sm.u.d.rowm[er])*sm.u.d.rowinv[er];
        __syncthreads();
        // 4: context[r][u] = sum_t alpha * a
        {
            float s0=0.f, s1=0.f;
            const u16* ap = &sm.a[cr][0][2*cup];
            const float* al = sm.u.d.alpha[cr];
            #pragma unroll 5
            for (int t=0;t<TX;t++){
                const u32 pa = *(const u32*)(ap + t*66);
                const float w = al[t];
                s0 += w*lo2f(pa); s1 += w*hi2f(pa);
            }
            sm.u.d.ctx[cr][2*cup] = s0; sm.u.d.ctx[cr][2*cup+1] = s1;
        }
        __syncthreads();
        // 5: post-cell gate dots (thread = gate tid, K = ctx 64 + s 64)
        {
            float acc[BT];
            #pragma unroll
            for (int r=0;r<BT;r++) acc[r] = pbias;
            const float4* c4 = (const float4*)&sm.u.d.ctx[0][0];
            #pragma unroll
            for (int k4=0;k4<16;k4++){
                const u32 p0 = wip[2*k4], p1 = wip[2*k4+1];
                const float w0=lo2f(p0), w1=hi2f(p0), w2v=lo2f(p1), w3=hi2f(p1);
                #pragma unroll
                for (int r=0;r<BT;r++){
                    const float4 xv = c4[r*17 + k4];
                    acc[r] += xv.x*w0 + xv.y*w1 + xv.z*w2v + xv.w*w3;
                }
            }
            const float4* s4 = (const float4*)&sm.u.d.s[0][0];
            #pragma unroll
            for (int k4=0;k4<16;k4++){
                const u32 p0 = whp[2*k4], p1 = whp[2*k4+1];
                const float w0=lo2f(p0), w1=hi2f(p0), w2v=lo2f(p1), w3=hi2f(p1);
                #pragma unroll
                for (int r=0;r<BT;r++){
                    const float4 xv = s4[r*17 + k4];
                    acc[r] += xv.x*w0 + xv.y*w1 + xv.z*w2v + xv.w*w3;
                }
            }
            #pragma unroll
            for (int r=0;r<BT;r++) sm.u.d.z2[r][tid] = acc[r];
        }
        __syncthreads();
        // 6: cell gates -> s, c (rows g2r and g2r+4)
        {
            const float* za = sm.u.d.z2[g2r];
            float i0=sigm(za[g2u]), f0=sigm(za[64+g2u]), g0=tanh_(za[128+g2u]), o0=sigm(za[192+g2u]);
            c2a = f0*c2a + i0*g0;
            sm.u.d.s[g2r][g2u] = o0*tanh_(c2a);
            const float* zb = sm.u.d.z2[g2r+4];
            float i1=sigm(zb[g2u]), f1=sigm(zb[64+g2u]), g1=tanh_(zb[128+g2u]), o1=sigm(zb[192+g2u]);
            c2b = f1*c2b + i1*g1;
            sm.u.d.s[g2r+4][g2u] = o1*tanh_(c2b);
        }
        __syncthreads();
        // 7: out = s @ Wo.T + bo
        {
            float a0 = sm.u.d.bof[g2u], a1 = a0;
            const float* s0 = sm.u.d.s[g2r];
            const float* s1 = sm.u.d.s[g2r+4];
            #pragma unroll 8
            for (int k=0;k<64;k++){
                const float w = lo2f((u32)sm.u.d.wof16[k][g2u] << 0 | 0u) ;
                // (lo2f of a bare u16 places it in the high bits correctly below)
                a0 += s0[k]*w; a1 += s1[k]*w;
            }
            out[(((long)(b0+g2r  ))*TY + ty)*64 + g2u] = a0;
            out[(((long)(b0+g2r+4))*TY + ty)*64 + g2u] = a1;
        }
    }
}

extern "C" void kernel_launch(void* const* d_in, const int* in_sizes, int n_in,
                              void* d_out, int out_size, void* d_ws, size_t ws_size,
                              hipStream_t stream) {
    const float* X    = (const float*)d_in[0];
    const float* Wihf = (const float*)d_in[1];
    const float* Whhf = (const float*)d_in[2];
    const float* bfv  = (const float*)d_in[3];
    const float* Wihr = (const float*)d_in[4];
    const float* Whhr = (const float*)d_in[5];
    const float* brv  = (const float*)d_in[6];
    const float* W1   = (const float*)d_in[7];
    const float* b1   = (const float*)d_in[8];
    const float* W2   = (const float*)d_in[9];
    const float* b2   = (const float*)d_in[10];
    const float* Wihp = (const float*)d_in[11];
    const float* Whhp = (const float*)d_in[12];
    const float* bp   = (const float*)d_in[13];
    const float* Wo   = (const float*)d_in[14];
    const float* bo   = (const float*)d_in[15];
    float* out = (float*)d_out;

    const int B = in_sizes[0] / (TX * 128);
    dim3 grid(B / BT), block(256);
    hipLaunchKernelGGL(fused_kernel, grid, block, 0, stream,
                       X, Wihf, Whhf, bfv, Wihr, Whhr, brv,
                       W1, b1, W2, b2, Wihp, Whhp, bp, Wo, bo, out);
}

// Round 4
// 854.516 us; speedup vs baseline: 2.8559x; 2.8559x over previous
//
#include <hip/hip_runtime.h>

typedef unsigned short u16;
typedef unsigned int   u32;
typedef __attribute__((ext_vector_type(8))) short short8;
typedef __attribute__((ext_vector_type(4))) float f4;

#define BT 8
#define TX 30
#define TY 10

__device__ __forceinline__ float bf2f_u16(u16 h){ u32 i=((u32)h)<<16; float f; __builtin_memcpy(&f,&i,4); return f; }
__device__ __forceinline__ float lo2f(u32 p){ u32 i=p<<16; float f; __builtin_memcpy(&f,&i,4); return f; }
__device__ __forceinline__ float hi2f(u32 p){ u32 i=p&0xffff0000u; float f; __builtin_memcpy(&f,&i,4); return f; }
__device__ __forceinline__ u16 f2bf(float f){ u32 x; __builtin_memcpy(&x,&f,4); u32 r=(x+0x7fffu+((x>>16)&1u))>>16; return (u16)r; }
__device__ __forceinline__ float sigm(float x){ return 1.0f/(1.0f+__expf(-x)); }
__device__ __forceinline__ float tanh_(float x){ x=fminf(fmaxf(x,-15.0f),15.0f); float e=__expf(2.0f*x); return (e-1.0f)/(e+1.0f); }
__device__ __forceinline__ f4 mfma16(short8 a, short8 b, f4 c){
    return __builtin_amdgcn_mfma_f32_16x16x32_bf16(a, b, c, 0, 0, 0);
}

union S8u { short8 s; u32 u[4]; };

// pack hi-halves of two fp32 into one u32 (truncated bf16 pair), residual -> lo pair
__device__ __forceinline__ void cvt_pair(float a0, float a1, u32& hp, u32& lp){
    u32 u0, u1; __builtin_memcpy(&u0,&a0,4); __builtin_memcpy(&u1,&a1,4);
    hp = __builtin_amdgcn_perm(u1, u0, 0x07060302u);          // [hi16(a1) : hi16(a0)]
    float r0 = a0 - hi2f(u0);
    float r1 = a1 - hi2f(u1);
    u32 v0, v1; __builtin_memcpy(&v0,&r0,4); __builtin_memcpy(&v1,&r1,4);
    lp = __builtin_amdgcn_perm(v1, v0, 0x07060302u);
}

struct SDec {
    float w1[10][132];          // W1 fp32 staged
    float aW1[BT][TX][10];      // b1 + a @ W1[:, :64].T  (ty-invariant)
    float s32[BT][66];          // decoder state fp32 (for sW1)
    u16 sh[16][72], sl[16][72]; // s hi/lo bf16, A-frag source [m][k]
    u16 ctxh[16][72], ctxl[16][72];
    float sW1[BT][12];
    float en[BT][32];
    float rowm[BT], rowinv[BT];
    float w2b[12]; float b2s;
};
struct SEnc {
    u16 h[2][2][2][16][40];     // [buf][dir][hi/lo][m][k], K=32 pad 40
};
union UU { SEnc e; SDec d; };
struct Smem {
    u16 a[BT][TX][72];          // encoder outputs bf16, k-stride 72 (144 B, 16-aligned rows)
    UU u;
};

__global__ __launch_bounds__(256, 2) void fused_kernel(
    const float* __restrict__ X,
    const float* __restrict__ Wihf, const float* __restrict__ Whhf, const float* __restrict__ bfv,
    const float* __restrict__ Wihr, const float* __restrict__ Whhr, const float* __restrict__ brv,
    const float* __restrict__ W1, const float* __restrict__ b1, const float* __restrict__ W2, const float* __restrict__ b2,
    const float* __restrict__ Wihp, const float* __restrict__ Whhp, const float* __restrict__ bp,
    const float* __restrict__ Wo, const float* __restrict__ bo,
    float* __restrict__ out)
{
    __shared__ __align__(16) Smem sm;
    const int tid = threadIdx.x;
    const int b0  = blockIdx.x * BT;

    {   // zero all LDS once: unwritten reads give 0, never garbage
        u32* p = (u32*)&sm;
        for (int i = tid; i < (int)(sizeof(Smem)/4); i += 256) p[i] = 0u;
    }
    __syncthreads();

    const int lane = tid & 63;
    const int wv   = tid >> 6;     // wave 0..3
    const int mL   = lane & 15;    // frag non-K index
    const int qL   = lane >> 4;    // quad
    const int k0q  = qL * 8;
    const int ed   = wv >> 1;      // encoder dir
    const int ub   = (wv & 1) * 16;// encoder unit base within NA=32

    // ===================== encoder =====================
    const float* Wih = ed ? Wihr : Wihf;
    const float* Whh = ed ? Whhr : Whhf;
    const float* bv  = ed ? brv  : bfv;

    short8 Bih[4][4]; short8 Bhh[4]; float bias4[4];
    #pragma unroll
    for (int gt = 0; gt < 4; gt++){
        const int n = gt*32 + ub + mL;                  // gate row (i,f,g,o chunks of 32)
        #pragma unroll
        for (int kt = 0; kt < 4; kt++){
            const float* p = Wih + n*128 + kt*32 + k0q;
            short8 s;
            #pragma unroll
            for (int j = 0; j < 8; j++) s[j] = (short)f2bf(p[j]);
            Bih[gt][kt] = s;
        }
        {
            const float* p = Whh + n*32 + k0q;
            short8 s;
            #pragma unroll
            for (int j = 0; j < 8; j++) s[j] = (short)f2bf(p[j]);
            Bhh[gt] = s;
        }
        bias4[gt] = bv[n];
    }

    const float* xrow = X + ((long)(b0 + (mL & 7))) * TX * 128;  // rows 8..15 duplicate 0..7 (discarded)
    float cst[4] = {0.f,0.f,0.f,0.f};

    auto estep = [&](int t, f4* cur, f4* nxt){
        if (t + 1 < TX){                                 // prefetch next x tile
            const int ts = ed ? (TX-2-t) : (t+1);
            const float* p = xrow + ts*128 + k0q;
            #pragma unroll
            for (int kt = 0; kt < 4; kt++){
                nxt[2*kt]   = *(const f4*)(p + kt*32);
                nxt[2*kt+1] = *(const f4*)(p + kt*32 + 4);
            }
        }
        const int rb = (t+1) & 1, wb = t & 1;
        const short8 Ahh = *(const short8*)&sm.u.e.h[rb][ed][0][mL][k0q];
        const short8 Ahl = *(const short8*)&sm.u.e.h[rb][ed][1][mL][k0q];

        f4 acc[4];
        #pragma unroll
        for (int gt = 0; gt < 4; gt++) acc[gt] = (f4){bias4[gt],bias4[gt],bias4[gt],bias4[gt]};

        #pragma unroll
        for (int kt = 0; kt < 4; kt++){
            S8u xh, xl;
            #pragma unroll
            for (int pp = 0; pp < 4; pp++){
                const f4 v = cur[2*kt + (pp>>1)];
                const int e = (pp & 1) * 2;
                cvt_pair(v[e], v[e+1], xh.u[pp], xl.u[pp]);
            }
            #pragma unroll
            for (int gt = 0; gt < 4; gt++){
                acc[gt] = mfma16(xh.s, Bih[gt][kt], acc[gt]);
                acc[gt] = mfma16(xl.s, Bih[gt][kt], acc[gt]);
            }
        }
        #pragma unroll
        for (int gt = 0; gt < 4; gt++){
            acc[gt] = mfma16(Ahh, Bhh[gt], acc[gt]);
            acc[gt] = mfma16(Ahl, Bhh[gt], acc[gt]);
        }

        const int tpos = ed ? (TX-1-t) : t;
        if (qL < 2){                                     // rows m = qL*4+reg in 0..7 valid
            #pragma unroll
            for (int reg = 0; reg < 4; reg++){
                const int m = qL*4 + reg;
                const float ii = sigm(acc[0][reg]), ff = sigm(acc[1][reg]);
                const float gg = tanh_(acc[2][reg]), oo = sigm(acc[3][reg]);
                cst[reg] = ff*cst[reg] + ii*gg;
                const float hh = oo * tanh_(cst[reg]);
                const u16 hhi = f2bf(hh);
                const u16 hlo = f2bf(hh - bf2f_u16(hhi));
                sm.u.e.h[wb][ed][0][m][ub+mL] = hhi;
                sm.u.e.h[wb][ed][1][m][ub+mL] = hlo;
                sm.a[m][tpos][ed*32 + ub + mL] = hhi;
            }
        }
        __syncthreads();
    };

    f4 rawA[8], rawB[8];
    {
        const int ts0 = ed ? (TX-1) : 0;
        const float* p = xrow + ts0*128 + k0q;
        #pragma unroll
        for (int kt = 0; kt < 4; kt++){
            rawA[2*kt]   = *(const f4*)(p + kt*32);
            rawA[2*kt+1] = *(const f4*)(p + kt*32 + 4);
        }
    }
    for (int t = 0; t < TX; t += 2){ estep(t, rawA, rawB); estep(t+1, rawB, rawA); }

    // ===================== decoder setup =====================
    for (int i = tid; i < 1280; i += 256){ const int j = i >> 7, k = i & 127; sm.u.d.w1[j][k] = W1[i]; }
    for (int i = tid; i < BT*66; i += 256) ((float*)sm.u.d.s32)[i] = 0.f;
    { u32* z = (u32*)sm.u.d.sh; for (int i = tid; i < 4*16*72/2; i += 256) z[i] = 0u; } // sh,sl,ctxh,ctxl
    if (tid < 10) sm.u.d.w2b[tid] = W2[tid];
    if (tid == 0) sm.u.d.b2s = b2[0];
    __syncthreads();

    if (tid < 240){                                      // aW1 = b1 + a @ W1[:, :64].T  (once)
        const int er = tid/30, et = tid - er*30;
        float accj[10];
        #pragma unroll
        for (int j = 0; j < 10; j++) accj[j] = b1[j];
        const u32* arow = (const u32*)&sm.a[er][et][0];
        for (int k2 = 0; k2 < 32; k2++){
            const u32 pa = arow[k2];
            const float a0 = lo2f(pa), a1 = hi2f(pa);
            #pragma unroll
            for (int j = 0; j < 10; j++)
                accj[j] += a0*sm.u.d.w1[j][2*k2] + a1*sm.u.d.w1[j][2*k2+1];
        }
        #pragma unroll
        for (int j = 0; j < 10; j++) sm.u.d.aW1[er][et][j] = accj[j];
    }

    const int uw = wv * 16;                              // decoder unit base (NS=64 over 4 waves)
    short8 Bip[4][2], Bhp[4][2]; float pb4[4];
    #pragma unroll
    for (int gt = 0; gt < 4; gt++){
        const int n = gt*64 + uw + mL;                   // post-cell gate row (chunks of 64)
        #pragma unroll
        for (int kt = 0; kt < 2; kt++){
            const float* p = Wihp + n*64 + kt*32 + k0q;
            const float* q = Whhp + n*64 + kt*32 + k0q;
            short8 s1v, s2v;
            #pragma unroll
            for (int j = 0; j < 8; j++){ s1v[j] = (short)f2bf(p[j]); s2v[j] = (short)f2bf(q[j]); }
            Bip[gt][kt] = s1v; Bhp[gt][kt] = s2v;
        }
        pb4[gt] = bp[n];
    }
    short8 Bo2[2];
    {
        const int n = uw + mL;
        #pragma unroll
        for (int kt = 0; kt < 2; kt++){
            const float* p = Wo + n*64 + kt*32 + k0q;
            short8 s;
            #pragma unroll
            for (int j = 0; j < 8; j++) s[j] = (short)f2bf(p[j]);
            Bo2[kt] = s;
        }
    }
    const float boL = bo[uw + mL];
    float cs2[4] = {0.f,0.f,0.f,0.f};
    __syncthreads();

    // ===================== decoder loop =====================
    for (int ty = 0; ty < TY; ty++){
        if (tid < 80){                                   // sW1 (no bias; bias folded in aW1/b1)
            const int r = tid/10, j = tid - r*10;
            const float* srow = sm.u.d.s32[r];
            const float* wrow = &sm.u.d.w1[j][64];
            float a = 0.f;
            #pragma unroll 8
            for (int k = 0; k < 64; k++) a += srow[k]*wrow[k];
            sm.u.d.sW1[r][j] = a;
        }
        __syncthreads();
        if (tid < 240){                                  // en = relu(tanh(aW1+sW1) . w2 + b2)
            const int er = tid/30, et = tid - er*30;
            float env = sm.u.d.b2s;
            #pragma unroll
            for (int j = 0; j < 10; j++){
                const float z = sm.u.d.aW1[er][et][j] + sm.u.d.sW1[er][j];
                env += sm.u.d.w2b[j]*tanh_(z);
            }
            sm.u.d.en[er][et] = fmaxf(env, 0.f);
        }
        __syncthreads();
        {   // softmax (inline, redundant per thread) + context + hi/lo frag write
            const int cr = tid >> 5, cup = tid & 31;
            const float* enr = sm.u.d.en[cr];
            float mx = enr[0];
            #pragma unroll
            for (int t2 = 1; t2 < TX; t2++) mx = fmaxf(mx, enr[t2]);
            float ssum = 0.f;
            #pragma unroll
            for (int t2 = 0; t2 < TX; t2++) ssum += __expf(enr[t2]-mx);
            const float inv = 1.0f/ssum;
            float s0 = 0.f, s1 = 0.f;
            const u16* ap = &sm.a[cr][0][2*cup];
            #pragma unroll 5
            for (int t2 = 0; t2 < TX; t2++){
                const u32 pa = *(const u32*)(ap + t2*72);
                const float w = __expf(enr[t2]-mx)*inv;
                s0 += w*lo2f(pa); s1 += w*hi2f(pa);
            }
            const u16 h0 = f2bf(s0), h1 = f2bf(s1);
            const u16 l0 = f2bf(s0 - bf2f_u16(h0)), l1 = f2bf(s1 - bf2f_u16(h1));
            *(u32*)&sm.u.d.ctxh[cr][2*cup] = (u32)h0 | ((u32)h1 << 16);
            *(u32*)&sm.u.d.ctxl[cr][2*cup] = (u32)l0 | ((u32)l1 << 16);
        }
        __syncthreads();
        // z2 = [ctx|s] @ Wp^T + bp   (in-register gates)
        f4 acc2[4];
        #pragma unroll
        for (int gt = 0; gt < 4; gt++) acc2[gt] = (f4){pb4[gt],pb4[gt],pb4[gt],pb4[gt]};
        #pragma unroll
        for (int kt = 0; kt < 2; kt++){
            const short8 ch  = *(const short8*)&sm.u.d.ctxh[mL][kt*32 + k0q];
            const short8 cl  = *(const short8*)&sm.u.d.ctxl[mL][kt*32 + k0q];
            const short8 shh = *(const short8*)&sm.u.d.sh[mL][kt*32 + k0q];
            const short8 sll = *(const short8*)&sm.u.d.sl[mL][kt*32 + k0q];
            #pragma unroll
            for (int gt = 0; gt < 4; gt++){
                acc2[gt] = mfma16(ch,  Bip[gt][kt], acc2[gt]);
                acc2[gt] = mfma16(cl,  Bip[gt][kt], acc2[gt]);
                acc2[gt] = mfma16(shh, Bhp[gt][kt], acc2[gt]);
                acc2[gt] = mfma16(sll, Bhp[gt][kt], acc2[gt]);
            }
        }
        __syncthreads();                                 // frag reads done before s overwrite
        if (qL < 2){
            #pragma unroll
            for (int reg = 0; reg < 4; reg++){
                const int m = qL*4 + reg;
                const float ii = sigm(acc2[0][reg]), ff = sigm(acc2[1][reg]);
                const float gg = tanh_(acc2[2][reg]), oo = sigm(acc2[3][reg]);
                cs2[reg] = ff*cs2[reg] + ii*gg;
                const float sv = oo * tanh_(cs2[reg]);
                const u16 shi = f2bf(sv);
                const u16 slo = f2bf(sv - bf2f_u16(shi));
                sm.u.d.s32[m][uw+mL] = sv;
                sm.u.d.sh[m][uw+mL]  = shi;
                sm.u.d.sl[m][uw+mL]  = slo;
            }
        }
        __syncthreads();
        // out = s @ Wo^T + bo
        f4 acc3 = (f4){boL, boL, boL, boL};
        #pragma unroll
        for (int kt = 0; kt < 2; kt++){
            const short8 shh = *(const short8*)&sm.u.d.sh[mL][kt*32 + k0q];
            const short8 sll = *(const short8*)&sm.u.d.sl[mL][kt*32 + k0q];
            acc3 = mfma16(shh, Bo2[kt], acc3);
            acc3 = mfma16(sll, Bo2[kt], acc3);
        }
        if (qL < 2){
            #pragma unroll
            for (int reg = 0; reg < 4; reg++){
                const int m = qL*4 + reg;
                out[(((long)(b0+m))*TY + ty)*64 + uw + mL] = acc3[reg];
            }
        }
    }
}

extern "C" void kernel_launch(void* const* d_in, const int* in_sizes, int n_in,
                              void* d_out, int out_size, void* d_ws, size_t ws_size,
                              hipStream_t stream) {
    const float* X    = (const float*)d_in[0];
    const float* Wihf = (const float*)d_in[1];
    const float* Whhf = (const float*)d_in[2];
    const float* bfv  = (const float*)d_in[3];
    const float* Wihr = (const float*)d_in[4];
    const float* Whhr = (const float*)d_in[5];
    const float* brv  = (const float*)d_in[6];
    const float* W1   = (const float*)d_in[7];
    const float* b1   = (const float*)d_in[8];
    const float* W2   = (const float*)d_in[9];
    const float* b2   = (const float*)d_in[10];
    const float* Wihp = (const float*)d_in[11];
    const float* Whhp = (const float*)d_in[12];
    const float* bp   = (const float*)d_in[13];
    const float* Wo   = (const float*)d_in[14];
    const float* bo   = (const float*)d_in[15];
    float* out = (float*)d_out;

    const int B = in_sizes[0] / (TX * 128);
    dim3 grid(B / BT), block(256);
    hipLaunchKernelGGL(fused_kernel, grid, block, 0, stream,
                       X, Wihf, Whhf, bfv, Wihr, Whhr, brv,
                       W1, b1, W2, b2, Wihp, Whhp, bp, Wo, bo, out);
}

// Round 5
// 778.558 us; speedup vs baseline: 3.1345x; 1.0976x over previous
//
#include <hip/hip_runtime.h>

typedef unsigned short u16;
typedef unsigned int   u32;
typedef __attribute__((ext_vector_type(8))) short short8;
typedef __attribute__((ext_vector_type(4))) float f4;

#define BT 8
#define TX 30
#define TY 10

__device__ __forceinline__ float bf2f_u16(u16 h){ u32 i=((u32)h)<<16; float f; __builtin_memcpy(&f,&i,4); return f; }
__device__ __forceinline__ float lo2f(u32 p){ u32 i=p<<16; float f; __builtin_memcpy(&f,&i,4); return f; }
__device__ __forceinline__ float hi2f(u32 p){ u32 i=p&0xffff0000u; float f; __builtin_memcpy(&f,&i,4); return f; }
__device__ __forceinline__ u16 f2bf(float f){ u32 x; __builtin_memcpy(&x,&f,4); u32 r=(x+0x7fffu+((x>>16)&1u))>>16; return (u16)r; }
__device__ __forceinline__ float sigm(float x){ return 1.0f/(1.0f+__expf(-x)); }
__device__ __forceinline__ float tanh_(float x){ x=fminf(fmaxf(x,-15.0f),15.0f); float e=__expf(2.0f*x); return (e-1.0f)/(e+1.0f); }
__device__ __forceinline__ f4 mfma16(short8 a, short8 b, f4 c){
    return __builtin_amdgcn_mfma_f32_16x16x32_bf16(a, b, c, 0, 0, 0);
}

union S8u { short8 s; u32 u[4]; };

// pack hi-halves of two fp32 into one u32 (truncated bf16 pair), residual -> lo pair
__device__ __forceinline__ void cvt_pair(float a0, float a1, u32& hp, u32& lp){
    u32 u0, u1; __builtin_memcpy(&u0,&a0,4); __builtin_memcpy(&u1,&a1,4);
    hp = __builtin_amdgcn_perm(u1, u0, 0x07060302u);          // [hi16(a1) : hi16(a0)]
    float r0 = a0 - hi2f(u0);
    float r1 = a1 - hi2f(u1);
    u32 v0, v1; __builtin_memcpy(&v0,&r0,4); __builtin_memcpy(&v1,&r1,4);
    lp = __builtin_amdgcn_perm(v1, v0, 0x07060302u);
}

struct SDec {
    float w1[10][132];          // W1 fp32 staged
    float aW1[BT][TX][10];      // b1 + a @ W1[:, :64].T  (ty-invariant)
    float s32[BT][66];          // decoder state fp32 (for sW1)
    u16 sh[16][72], sl[16][72]; // s hi/lo bf16, A-frag source [m][k]
    u16 ctxh[16][72], ctxl[16][72];
    float sW1[BT][12];
    float en[BT][32];
    float w2b[12]; float b2s;
};
struct SEnc {
    u16 h[2][2][2][BT][40];     // [parity][dir][hi/lo][m][k], K=32 pad 40
    u16 zr[40];                 // always-zero row (A-frag filler)
    float cf[2][BT][36];        // LSTM c state [dir][m][unit]
};
union UU { SEnc e; SDec d; };
struct Smem {
    u16 a[BT][TX][72];          // encoder outputs bf16
    UU u;
};

__global__ __launch_bounds__(256, 2) void fused_kernel(
    const float* __restrict__ X,
    const float* __restrict__ Wihf, const float* __restrict__ Whhf, const float* __restrict__ bfv,
    const float* __restrict__ Wihr, const float* __restrict__ Whhr, const float* __restrict__ brv,
    const float* __restrict__ W1, const float* __restrict__ b1, const float* __restrict__ W2, const float* __restrict__ b2,
    const float* __restrict__ Wihp, const float* __restrict__ Whhp, const float* __restrict__ bp,
    const float* __restrict__ Wo, const float* __restrict__ bo,
    float* __restrict__ out)
{
    __shared__ __align__(16) Smem sm;
    const int tid = threadIdx.x;
    const int b0  = blockIdx.x * BT;

    {   // zero all LDS once (h bufs, zr, cf must start 0; unwritten reads never garbage)
        u32* p = (u32*)&sm;
        for (int i = tid; i < (int)(sizeof(Smem)/4); i += 256) p[i] = 0u;
    }
    __syncthreads();

    const int lane = tid & 63;
    const int wv   = tid >> 6;     // wave 0..3
    const int mL   = lane & 15;    // frag non-K index
    const int qL   = lane >> 4;    // quad
    const int k0q  = qL * 8;
    const int ed   = wv >> 1;      // encoder dir
    const int ub   = (wv & 1) * 16;// encoder unit base within NA=32
    const int sstep= mL >> 3;      // 0: step t rows, 1: step t+1 rows

    // ===================== encoder =====================
    const float* Wih = ed ? Wihr : Wihf;
    const float* Whh = ed ? Whhr : Whhf;
    const float* bv  = ed ? brv  : bfv;

    short8 Bih[4][4]; short8 Bhh[4]; float bias4[4];
    #pragma unroll
    for (int gt = 0; gt < 4; gt++){
        const int n = gt*32 + ub + mL;                  // gate row (i,f,g,o chunks of 32)
        #pragma unroll
        for (int kt = 0; kt < 4; kt++){
            const float* p = Wih + n*128 + kt*32 + k0q;
            short8 s;
            #pragma unroll
            for (int j = 0; j < 8; j++) s[j] = (short)f2bf(p[j]);
            Bih[gt][kt] = s;
        }
        {
            const float* p = Whh + n*32 + k0q;
            short8 s;
            #pragma unroll
            for (int j = 0; j < 8; j++) s[j] = (short)f2bf(p[j]);
            Bhh[gt] = s;
        }
        bias4[gt] = bv[n];
    }

    const float* xrow = X + ((long)(b0 + (mL & 7))) * TX * 128;  // rows 8-15: same batch row, step t+1

    // pair processor: steps (t, t+1); M rows 0-7 = step t, 8-15 = step t+1
    auto epair = [&](int t, f4* cur, f4* nxt){
        if (t + 2 < TX){                                 // prefetch next pair
            const int ts = ed ? (TX-1-(t+2+sstep)) : (t+2+sstep);
            const float* p = xrow + ts*128 + k0q;
            #pragma unroll
            for (int kt = 0; kt < 4; kt++){
                nxt[2*kt]   = *(const f4*)(p + kt*32);
                nxt[2*kt+1] = *(const f4*)(p + kt*32 + 4);
            }
        }
        const int rb = (t+1) & 1, wb = t & 1;            // h_{t-1} in buf rb; h_t -> buf wb; h_{t+1} -> buf rb

        f4 acc[4];
        #pragma unroll
        for (int gt = 0; gt < 4; gt++) acc[gt] = (f4){bias4[gt],bias4[gt],bias4[gt],bias4[gt]};

        #pragma unroll
        for (int kt = 0; kt < 4; kt++){                  // x-GEMM, both steps at once
            S8u xh, xl;
            #pragma unroll
            for (int pp = 0; pp < 4; pp++){
                const f4 v = cur[2*kt + (pp>>1)];
                const int e = (pp & 1) * 2;
                cvt_pair(v[e], v[e+1], xh.u[pp], xl.u[pp]);
            }
            #pragma unroll
            for (int gt = 0; gt < 4; gt++){
                acc[gt] = mfma16(xh.s, Bih[gt][kt], acc[gt]);
                acc[gt] = mfma16(xl.s, Bih[gt][kt], acc[gt]);
            }
        }
        {   // h-MFMA step t: A rows 0-7 = h_{t-1}, rows 8-15 = 0
            const short8 Ahh = *(const short8*)((mL < 8) ? &sm.u.e.h[rb][ed][0][mL][k0q] : &sm.u.e.zr[k0q]);
            const short8 Ahl = *(const short8*)((mL < 8) ? &sm.u.e.h[rb][ed][1][mL][k0q] : &sm.u.e.zr[k0q]);
            #pragma unroll
            for (int gt = 0; gt < 4; gt++){
                acc[gt] = mfma16(Ahh, Bhh[gt], acc[gt]);
                acc[gt] = mfma16(Ahl, Bhh[gt], acc[gt]);
            }
        }
        if (qL < 2){                                     // cell update step t (rows 0-7)
            const int tpos = ed ? (TX-1-t) : t;
            #pragma unroll
            for (int reg = 0; reg < 4; reg++){
                const int m = qL*4 + reg;
                float c = sm.u.e.cf[ed][m][ub+mL];
                const float ii = sigm(acc[0][reg]), ff = sigm(acc[1][reg]);
                const float gg = tanh_(acc[2][reg]), oo = sigm(acc[3][reg]);
                c = ff*c + ii*gg;
                const float hh = oo * tanh_(c);
                sm.u.e.cf[ed][m][ub+mL] = c;
                const u16 hhi = f2bf(hh);
                const u16 hlo = f2bf(hh - bf2f_u16(hhi));
                sm.u.e.h[wb][ed][0][m][ub+mL] = hhi;
                sm.u.e.h[wb][ed][1][m][ub+mL] = hlo;
                sm.a[m][tpos][ed*32 + ub + mL] = hhi;
            }
        }
        __syncthreads();
        {   // h-MFMA step t+1: A rows 8-15 = h_t, rows 0-7 = 0
            const short8 Ahh = *(const short8*)((mL >= 8) ? &sm.u.e.h[wb][ed][0][mL-8][k0q] : &sm.u.e.zr[k0q]);
            const short8 Ahl = *(const short8*)((mL >= 8) ? &sm.u.e.h[wb][ed][1][mL-8][k0q] : &sm.u.e.zr[k0q]);
            #pragma unroll
            for (int gt = 0; gt < 4; gt++){
                acc[gt] = mfma16(Ahh, Bhh[gt], acc[gt]);
                acc[gt] = mfma16(Ahl, Bhh[gt], acc[gt]);
            }
        }
        if (qL >= 2){                                    // cell update step t+1 (rows 8-15)
            const int tpos = ed ? (TX-2-t) : (t+1);
            #pragma unroll
            for (int reg = 0; reg < 4; reg++){
                const int m = (qL-2)*4 + reg;
                float c = sm.u.e.cf[ed][m][ub+mL];
                const float ii = sigm(acc[0][reg]), ff = sigm(acc[1][reg]);
                const float gg = tanh_(acc[2][reg]), oo = sigm(acc[3][reg]);
                c = ff*c + ii*gg;
                const float hh = oo * tanh_(c);
                sm.u.e.cf[ed][m][ub+mL] = c;
                const u16 hhi = f2bf(hh);
                const u16 hlo = f2bf(hh - bf2f_u16(hhi));
                sm.u.e.h[rb][ed][0][m][ub+mL] = hhi;
                sm.u.e.h[rb][ed][1][m][ub+mL] = hlo;
                sm.a[m][tpos][ed*32 + ub + mL] = hhi;
            }
        }
        __syncthreads();
    };

    f4 rawA[8], rawB[8];
    {   // initial pair load
        const int ts0 = ed ? (TX-1-sstep) : sstep;
        const float* p = xrow + ts0*128 + k0q;
        #pragma unroll
        for (int kt = 0; kt < 4; kt++){
            rawA[2*kt]   = *(const f4*)(p + kt*32);
            rawA[2*kt+1] = *(const f4*)(p + kt*32 + 4);
        }
    }
    for (int tp = 0; tp < 28; tp += 4){ epair(tp, rawA, rawB); epair(tp+2, rawB, rawA); }
    epair(28, rawA, rawB);                               // last pair (no prefetch)

    // ===================== decoder setup =====================
    for (int i = tid; i < 1280; i += 256){ const int j = i >> 7, k = i & 127; sm.u.d.w1[j][k] = W1[i]; }
    for (int i = tid; i < BT*66; i += 256) ((float*)sm.u.d.s32)[i] = 0.f;
    { u32* z = (u32*)sm.u.d.sh; for (int i = tid; i < 4*16*72/2; i += 256) z[i] = 0u; } // sh,sl,ctxh,ctxl
    if (tid < 10) sm.u.d.w2b[tid] = W2[tid];
    if (tid == 0) sm.u.d.b2s = b2[0];
    __syncthreads();

    if (tid < 240){                                      // aW1 = b1 + a @ W1[:, :64].T  (once)
        const int er = tid/30, et = tid - er*30;
        float accj[10];
        #pragma unroll
        for (int j = 0; j < 10; j++) accj[j] = b1[j];
        const u32* arow = (const u32*)&sm.a[er][et][0];
        for (int k2 = 0; k2 < 32; k2++){
            const u32 pa = arow[k2];
            const float a0 = lo2f(pa), a1 = hi2f(pa);
            #pragma unroll
            for (int j = 0; j < 10; j++)
                accj[j] += a0*sm.u.d.w1[j][2*k2] + a1*sm.u.d.w1[j][2*k2+1];
        }
        #pragma unroll
        for (int j = 0; j < 10; j++) sm.u.d.aW1[er][et][j] = accj[j];
    }

    const int uw = wv * 16;                              // decoder unit base (NS=64 over 4 waves)
    short8 Bip[4][2], Bhp[4][2]; float pb4[4];
    #pragma unroll
    for (int gt = 0; gt < 4; gt++){
        const int n = gt*64 + uw + mL;                   // post-cell gate row (chunks of 64)
        #pragma unroll
        for (int kt = 0; kt < 2; kt++){
            const float* p = Wihp + n*64 + kt*32 + k0q;
            const float* q = Whhp + n*64 + kt*32 + k0q;
            short8 s1v, s2v;
            #pragma unroll
            for (int j = 0; j < 8; j++){ s1v[j] = (short)f2bf(p[j]); s2v[j] = (short)f2bf(q[j]); }
            Bip[gt][kt] = s1v; Bhp[gt][kt] = s2v;
        }
        pb4[gt] = bp[n];
    }
    short8 Bo2[2];
    {
        const int n = uw + mL;
        #pragma unroll
        for (int kt = 0; kt < 2; kt++){
            const float* p = Wo + n*64 + kt*32 + k0q;
            short8 s;
            #pragma unroll
            for (int j = 0; j < 8; j++) s[j] = (short)f2bf(p[j]);
            Bo2[kt] = s;
        }
    }
    const float boL = bo[uw + mL];
    float cs2[4] = {0.f,0.f,0.f,0.f};
    __syncthreads();

    // ===================== decoder loop =====================
    for (int ty = 0; ty < TY; ty++){
        if (tid < 80){                                   // sW1: 4 partial sums break dep chain
            const int r = tid/10, j = tid - r*10;
            const float* srow = sm.u.d.s32[r];
            const float* wrow = &sm.u.d.w1[j][64];
            float a0 = 0.f, a1 = 0.f, a2 = 0.f, a3 = 0.f;
            #pragma unroll
            for (int k = 0; k < 64; k += 4){
                a0 += srow[k]*wrow[k];     a1 += srow[k+1]*wrow[k+1];
                a2 += srow[k+2]*wrow[k+2]; a3 += srow[k+3]*wrow[k+3];
            }
            sm.u.d.sW1[r][j] = (a0+a1)+(a2+a3);
        }
        __syncthreads();
        if (tid < 240){                                  // en = relu(tanh(aW1+sW1) . w2 + b2)
            const int er = tid/30, et = tid - er*30;
            float env = sm.u.d.b2s;
            #pragma unroll
            for (int j = 0; j < 10; j++){
                const float z = sm.u.d.aW1[er][et][j] + sm.u.d.sW1[er][j];
                env += sm.u.d.w2b[j]*tanh_(z);
            }
            sm.u.d.en[er][et] = fmaxf(env, 0.f);
        }
        __syncthreads();
        {   // softmax (inline) + context + hi/lo frag write
            const int cr = tid >> 5, cup = tid & 31;
            const float* enr = sm.u.d.en[cr];
            float mx = enr[0];
            #pragma unroll
            for (int t2 = 1; t2 < TX; t2++) mx = fmaxf(mx, enr[t2]);
            float ssum = 0.f;
            #pragma unroll
            for (int t2 = 0; t2 < TX; t2++) ssum += __expf(enr[t2]-mx);
            const float inv = 1.0f/ssum;
            float s0 = 0.f, s1 = 0.f;
            const u16* ap = &sm.a[cr][0][2*cup];
            #pragma unroll 5
            for (int t2 = 0; t2 < TX; t2++){
                const u32 pa = *(const u32*)(ap + t2*72);
                const float w = __expf(enr[t2]-mx)*inv;
                s0 += w*lo2f(pa); s1 += w*hi2f(pa);
            }
            const u16 h0 = f2bf(s0), h1 = f2bf(s1);
            const u16 l0 = f2bf(s0 - bf2f_u16(h0)), l1 = f2bf(s1 - bf2f_u16(h1));
            *(u32*)&sm.u.d.ctxh[cr][2*cup] = (u32)h0 | ((u32)h1 << 16);
            *(u32*)&sm.u.d.ctxl[cr][2*cup] = (u32)l0 | ((u32)l1 << 16);
        }
        __syncthreads();
        // z2 = [ctx|s] @ Wp^T + bp   (in-register gates)
        f4 acc2[4];
        #pragma unroll
        for (int gt = 0; gt < 4; gt++) acc2[gt] = (f4){pb4[gt],pb4[gt],pb4[gt],pb4[gt]};
        #pragma unroll
        for (int kt = 0; kt < 2; kt++){
            const short8 ch  = *(const short8*)&sm.u.d.ctxh[mL][kt*32 + k0q];
            const short8 cl  = *(const short8*)&sm.u.d.ctxl[mL][kt*32 + k0q];
            const short8 shh = *(const short8*)&sm.u.d.sh[mL][kt*32 + k0q];
            const short8 sll = *(const short8*)&sm.u.d.sl[mL][kt*32 + k0q];
            #pragma unroll
            for (int gt = 0; gt < 4; gt++){
                acc2[gt] = mfma16(ch,  Bip[gt][kt], acc2[gt]);
                acc2[gt] = mfma16(cl,  Bip[gt][kt], acc2[gt]);
                acc2[gt] = mfma16(shh, Bhp[gt][kt], acc2[gt]);
                acc2[gt] = mfma16(sll, Bhp[gt][kt], acc2[gt]);
            }
        }
        __syncthreads();                                 // frag reads done before s overwrite
        if (qL < 2){
            #pragma unroll
            for (int reg = 0; reg < 4; reg++){
                const int m = qL*4 + reg;
                const float ii = sigm(acc2[0][reg]), ff = sigm(acc2[1][reg]);
                const float gg = tanh_(acc2[2][reg]), oo = sigm(acc2[3][reg]);
                cs2[reg] = ff*cs2[reg] + ii*gg;
                const float sv = oo * tanh_(cs2[reg]);
                const u16 shi = f2bf(sv);
                const u16 slo = f2bf(sv - bf2f_u16(shi));
                sm.u.d.s32[m][uw+mL] = sv;
                sm.u.d.sh[m][uw+mL]  = shi;
                sm.u.d.sl[m][uw+mL]  = slo;
            }
        }
        __syncthreads();
        // out = s @ Wo^T + bo
        f4 acc3 = (f4){boL, boL, boL, boL};
        #pragma unroll
        for (int kt = 0; kt < 2; kt++){
            const short8 shh = *(const short8*)&sm.u.d.sh[mL][kt*32 + k0q];
            const short8 sll = *(const short8*)&sm.u.d.sl[mL][kt*32 + k0q];
            acc3 = mfma16(shh, Bo2[kt], acc3);
            acc3 = mfma16(sll, Bo2[kt], acc3);
        }
        if (qL < 2){
            #pragma unroll
            for (int reg = 0; reg < 4; reg++){
                const int m = qL*4 + reg;
                out[(((long)(b0+m))*TY + ty)*64 + uw + mL] = acc3[reg];
            }
        }
    }
}

extern "C" void kernel_launch(void* const* d_in, const int* in_sizes, int n_in,
                              void* d_out, int out_size, void* d_ws, size_t ws_size,
                              hipStream_t stream) {
    const float* X    = (const float*)d_in[0];
    const float* Wihf = (const float*)d_in[1];
    const float* Whhf = (const float*)d_in[2];
    const float* bfv  = (const float*)d_in[3];
    const float* Wihr = (const float*)d_in[4];
    const float* Whhr = (const float*)d_in[5];
    const float* brv  = (const float*)d_in[6];
    const float* W1   = (const float*)d_in[7];
    const float* b1   = (const float*)d_in[8];
    const float* W2   = (const float*)d_in[9];
    const float* b2   = (const float*)d_in[10];
    const float* Wihp = (const float*)d_in[11];
    const float* Whhp = (const float*)d_in[12];
    const float* bp   = (const float*)d_in[13];
    const float* Wo   = (const float*)d_in[14];
    const float* bo   = (const float*)d_in[15];
    float* out = (float*)d_out;

    const int B = in_sizes[0] / (TX * 128);
    dim3 grid(B / BT), block(256);
    hipLaunchKernelGGL(fused_kernel, grid, block, 0, stream,
                       X, Wihf, Whhf, bfv, Wihr, Whhr, brv,
                       W1, b1, W2, b2, Wihp, Whhp, bp, Wo, bo, out);
}

// Round 6
// 653.211 us; speedup vs baseline: 3.7360x; 1.1919x over previous
//
#include <hip/hip_runtime.h>

typedef unsigned short u16;
typedef unsigned int   u32;
typedef __attribute__((ext_vector_type(8))) short short8;
typedef __attribute__((ext_vector_type(4))) float f4;

#define BT 8
#define TX 30
#define TY 10

__device__ __forceinline__ float bf2f_u16(u16 h){ u32 i=((u32)h)<<16; float f; __builtin_memcpy(&f,&i,4); return f; }
__device__ __forceinline__ float lo2f(u32 p){ u32 i=p<<16; float f; __builtin_memcpy(&f,&i,4); return f; }
__device__ __forceinline__ float hi2f(u32 p){ u32 i=p&0xffff0000u; float f; __builtin_memcpy(&f,&i,4); return f; }
__device__ __forceinline__ u16 f2bf(float f){ u32 x; __builtin_memcpy(&x,&f,4); u32 r=(x+0x7fffu+((x>>16)&1u))>>16; return (u16)r; }

#if __has_builtin(__builtin_amdgcn_rcpf)
__device__ __forceinline__ float frcp(float x){ return __builtin_amdgcn_rcpf(x); }
#else
__device__ __forceinline__ float frcp(float x){ return 1.0f/x; }
#endif
// fast activations: single v_exp + v_rcp (no fp32 div sequence)
__device__ __forceinline__ float sigm(float x){ return frcp(1.0f+__expf(-x)); }
__device__ __forceinline__ float tanh_(float x){ x=fminf(fmaxf(x,-15.0f),15.0f); float e=__expf(2.0f*x); return 1.0f - 2.0f*frcp(e+1.0f); }

__device__ __forceinline__ f4 mfma16(short8 a, short8 b, f4 c){
    return __builtin_amdgcn_mfma_f32_16x16x32_bf16(a, b, c, 0, 0, 0);
}

union S8u { short8 s; u32 u[4]; };

// pack hi-halves of two fp32 into one u32 (truncated bf16 pair), residual -> lo pair
__device__ __forceinline__ void cvt_pair(float a0, float a1, u32& hp, u32& lp){
    u32 u0, u1; __builtin_memcpy(&u0,&a0,4); __builtin_memcpy(&u1,&a1,4);
    hp = __builtin_amdgcn_perm(u1, u0, 0x07060302u);          // [hi16(a1) : hi16(a0)]
    float r0 = a0 - hi2f(u0);
    float r1 = a1 - hi2f(u1);
    u32 v0, v1; __builtin_memcpy(&v0,&r0,4); __builtin_memcpy(&v1,&r1,4);
    lp = __builtin_amdgcn_perm(v1, v0, 0x07060302u);
}

struct SDec {
    float w1[10][132];          // W1 fp32 staged (for aW1 precompute)
    float aW1[BT][TX][10];      // b1 + a @ W1[:, :64].T  (ty-invariant)
    u16 sh[16][72], sl[16][72]; // s hi/lo bf16, A-frag source [m][k]
    u16 ctxh[16][72], ctxl[16][72];
    float sW1[BT][12];
    float en[BT][32];
    float w2b[12]; float b2s;
};
struct SEnc {
    u16 h[2][2][2][BT][40];     // [parity][dir][hi/lo][m][k], K=32 pad 40
    u16 zr[40];                 // always-zero row (A-frag filler)
};
union UU { SEnc e; SDec d; };
struct Smem {
    u16 a[BT][TX][72];          // encoder outputs bf16
    UU u;
};

__global__ __launch_bounds__(256, 2) void fused_kernel(
    const float* __restrict__ X,
    const float* __restrict__ Wihf, const float* __restrict__ Whhf, const float* __restrict__ bfv,
    const float* __restrict__ Wihr, const float* __restrict__ Whhr, const float* __restrict__ brv,
    const float* __restrict__ W1, const float* __restrict__ b1, const float* __restrict__ W2, const float* __restrict__ b2,
    const float* __restrict__ Wihp, const float* __restrict__ Whhp, const float* __restrict__ bp,
    const float* __restrict__ Wo, const float* __restrict__ bo,
    float* __restrict__ out)
{
    __shared__ __align__(16) Smem sm;
    const int tid = threadIdx.x;
    const int b0  = blockIdx.x * BT;

    {   // zero all LDS once (h bufs, zr must start 0; unwritten reads never garbage)
        u32* p = (u32*)&sm;
        for (int i = tid; i < (int)(sizeof(Smem)/4); i += 256) p[i] = 0u;
    }
    __syncthreads();

    const int lane = tid & 63;
    const int wv   = tid >> 6;     // wave 0..3
    const int mL   = lane & 15;    // frag non-K index
    const int qL   = lane >> 4;    // quad
    const int k0q  = qL * 8;
    const int ed   = wv >> 1;      // encoder dir
    const int ub   = (wv & 1) * 16;// encoder unit base within NA=32
    const int sstep= mL >> 3;      // 0: step t rows, 1: step t+1 rows

    // ===================== encoder =====================
    const float* Wih = ed ? Wihr : Wihf;
    const float* Whh = ed ? Whhr : Whhf;
    const float* bv  = ed ? brv  : bfv;

    short8 Bih[4][4]; short8 Bhh[4]; float bias4[4];
    #pragma unroll
    for (int gt = 0; gt < 4; gt++){
        const int n = gt*32 + ub + mL;                  // gate row (i,f,g,o chunks of 32)
        #pragma unroll
        for (int kt = 0; kt < 4; kt++){
            const float* p = Wih + n*128 + kt*32 + k0q;
            short8 s;
            #pragma unroll
            for (int j = 0; j < 8; j++) s[j] = (short)f2bf(p[j]);
            Bih[gt][kt] = s;
        }
        {
            const float* p = Whh + n*32 + k0q;
            short8 s;
            #pragma unroll
            for (int j = 0; j < 8; j++) s[j] = (short)f2bf(p[j]);
            Bhh[gt] = s;
        }
        bias4[gt] = bv[n];
    }

    const float* xrow = X + ((long)(b0 + (mL & 7))) * TX * 128;  // rows 8-15: same batch row, step t+1
    float cst[4] = {0.f,0.f,0.f,0.f};  // c-state: lives in qL<2 lanes before even steps, swaps via shfl_xor 32

    // pair processor: steps (t, t+1); M rows 0-7 = step t, 8-15 = step t+1
    auto epair = [&](int t, f4* cur, f4* nxt){
        if (t + 2 < TX){                                 // prefetch next pair
            const int ts = ed ? (TX-1-(t+2+sstep)) : (t+2+sstep);
            const float* p = xrow + ts*128 + k0q;
            #pragma unroll
            for (int kt = 0; kt < 4; kt++){
                nxt[2*kt]   = *(const f4*)(p + kt*32);
                nxt[2*kt+1] = *(const f4*)(p + kt*32 + 4);
            }
        }
        const int rb = (t+1) & 1, wb = t & 1;            // h_{t-1} in buf rb; h_t -> buf wb; h_{t+1} -> buf rb

        f4 acc[4];
        #pragma unroll
        for (int gt = 0; gt < 4; gt++) acc[gt] = (f4){bias4[gt],bias4[gt],bias4[gt],bias4[gt]};

        #pragma unroll
        for (int kt = 0; kt < 4; kt++){                  // x-GEMM, both steps at once
            S8u xh, xl;
            #pragma unroll
            for (int pp = 0; pp < 4; pp++){
                const f4 v = cur[2*kt + (pp>>1)];
                const int e = (pp & 1) * 2;
                cvt_pair(v[e], v[e+1], xh.u[pp], xl.u[pp]);
            }
            #pragma unroll
            for (int gt = 0; gt < 4; gt++){
                acc[gt] = mfma16(xh.s, Bih[gt][kt], acc[gt]);
                acc[gt] = mfma16(xl.s, Bih[gt][kt], acc[gt]);
            }
        }
        {   // h-MFMA step t: A rows 0-7 = h_{t-1}, rows 8-15 = 0
            const short8 Ahh = *(const short8*)((mL < 8) ? &sm.u.e.h[rb][ed][0][mL][k0q] : &sm.u.e.zr[k0q]);
            const short8 Ahl = *(const short8*)((mL < 8) ? &sm.u.e.h[rb][ed][1][mL][k0q] : &sm.u.e.zr[k0q]);
            #pragma unroll
            for (int gt = 0; gt < 4; gt++){
                acc[gt] = mfma16(Ahh, Bhh[gt], acc[gt]);
                acc[gt] = mfma16(Ahl, Bhh[gt], acc[gt]);
            }
        }
        if (qL < 2){                                     // cell update step t (rows 0-7)
            const int tpos = ed ? (TX-1-t) : t;
            #pragma unroll
            for (int reg = 0; reg < 4; reg++){
                const int m = qL*4 + reg;
                const float ii = sigm(acc[0][reg]), ff = sigm(acc[1][reg]);
                const float gg = tanh_(acc[2][reg]), oo = sigm(acc[3][reg]);
                cst[reg] = ff*cst[reg] + ii*gg;
                const float hh = oo * tanh_(cst[reg]);
                const u16 hhi = f2bf(hh);
                const u16 hlo = f2bf(hh - bf2f_u16(hhi));
                sm.u.e.h[wb][ed][0][m][ub+mL] = hhi;
                sm.u.e.h[wb][ed][1][m][ub+mL] = hlo;
                sm.a[m][tpos][ed*32 + ub + mL] = hhi;
            }
        }
        #pragma unroll
        for (int reg = 0; reg < 4; reg++) cst[reg] = __shfl_xor(cst[reg], 32);  // c -> qL>=2 lanes
        __syncthreads();
        {   // h-MFMA step t+1: A rows 8-15 = h_t, rows 0-7 = 0
            const short8 Ahh = *(const short8*)((mL >= 8) ? &sm.u.e.h[wb][ed][0][mL-8][k0q] : &sm.u.e.zr[k0q]);
            const short8 Ahl = *(const short8*)((mL >= 8) ? &sm.u.e.h[wb][ed][1][mL-8][k0q] : &sm.u.e.zr[k0q]);
            #pragma unroll
            for (int gt = 0; gt < 4; gt++){
                acc[gt] = mfma16(Ahh, Bhh[gt], acc[gt]);
                acc[gt] = mfma16(Ahl, Bhh[gt], acc[gt]);
            }
        }
        if (qL >= 2){                                    // cell update step t+1 (rows 8-15)
            const int tpos = ed ? (TX-2-t) : (t+1);
            #pragma unroll
            for (int reg = 0; reg < 4; reg++){
                const int m = (qL-2)*4 + reg;
                const float ii = sigm(acc[0][reg]), ff = sigm(acc[1][reg]);
                const float gg = tanh_(acc[2][reg]), oo = sigm(acc[3][reg]);
                cst[reg] = ff*cst[reg] + ii*gg;
                const float hh = oo * tanh_(cst[reg]);
                const u16 hhi = f2bf(hh);
                const u16 hlo = f2bf(hh - bf2f_u16(hhi));
                sm.u.e.h[rb][ed][0][m][ub+mL] = hhi;
                sm.u.e.h[rb][ed][1][m][ub+mL] = hlo;
                sm.a[m][tpos][ed*32 + ub + mL] = hhi;
            }
        }
        #pragma unroll
        for (int reg = 0; reg < 4; reg++) cst[reg] = __shfl_xor(cst[reg], 32);  // c -> qL<2 lanes
        __syncthreads();
    };

    f4 rawA[8], rawB[8];
    {   // initial pair load
        const int ts0 = ed ? (TX-1-sstep) : sstep;
        const float* p = xrow + ts0*128 + k0q;
        #pragma unroll
        for (int kt = 0; kt < 4; kt++){
            rawA[2*kt]   = *(const f4*)(p + kt*32);
            rawA[2*kt+1] = *(const f4*)(p + kt*32 + 4);
        }
    }
    for (int tp = 0; tp < 28; tp += 4){ epair(tp, rawA, rawB); epair(tp+2, rawB, rawA); }
    epair(28, rawA, rawB);                               // last pair (no prefetch)

    // ===================== decoder setup =====================
    for (int i = tid; i < 1280; i += 256){ const int j = i >> 7, k = i & 127; sm.u.d.w1[j][k] = W1[i]; }
    { u32* z = (u32*)sm.u.d.sh; for (int i = tid; i < 4*16*72/2; i += 256) z[i] = 0u; } // sh,sl,ctxh,ctxl
    if (tid < 10) sm.u.d.w2b[tid] = W2[tid];
    if (tid == 0) sm.u.d.b2s = b2[0];
    __syncthreads();

    if (tid < 240){                                      // aW1 = b1 + a @ W1[:, :64].T  (once)
        const int er = tid/30, et = tid - er*30;
        float accj[10];
        #pragma unroll
        for (int j = 0; j < 10; j++) accj[j] = b1[j];
        const u32* arow = (const u32*)&sm.a[er][et][0];
        for (int k2 = 0; k2 < 32; k2++){
            const u32 pa = arow[k2];
            const float a0 = lo2f(pa), a1 = hi2f(pa);
            #pragma unroll
            for (int j = 0; j < 10; j++)
                accj[j] += a0*sm.u.d.w1[j][2*k2] + a1*sm.u.d.w1[j][2*k2+1];
        }
        #pragma unroll
        for (int j = 0; j < 10; j++) sm.u.d.aW1[er][et][j] = accj[j];
    }

    const int uw = wv * 16;                              // decoder unit base (NS=64 over 4 waves)
    short8 Bip[4][2], Bhp[4][2]; float pb4[4];
    #pragma unroll
    for (int gt = 0; gt < 4; gt++){
        const int n = gt*64 + uw + mL;                   // post-cell gate row (chunks of 64)
        #pragma unroll
        for (int kt = 0; kt < 2; kt++){
            const float* p = Wihp + n*64 + kt*32 + k0q;
            const float* q = Whhp + n*64 + kt*32 + k0q;
            short8 s1v, s2v;
            #pragma unroll
            for (int j = 0; j < 8; j++){ s1v[j] = (short)f2bf(p[j]); s2v[j] = (short)f2bf(q[j]); }
            Bip[gt][kt] = s1v; Bhp[gt][kt] = s2v;
        }
        pb4[gt] = bp[n];
    }
    short8 Bo2[2];
    {
        const int n = uw + mL;
        #pragma unroll
        for (int kt = 0; kt < 2; kt++){
            const float* p = Wo + n*64 + kt*32 + k0q;
            short8 s;
            #pragma unroll
            for (int j = 0; j < 8; j++) s[j] = (short)f2bf(p[j]);
            Bo2[kt] = s;
        }
    }
    short8 W1sB[2];                                      // B-frag of W1[:,64:128], n=mL (rows>=10 zero)
    #pragma unroll
    for (int kt = 0; kt < 2; kt++){
        short8 s;
        #pragma unroll
        for (int j = 0; j < 8; j++){
            const float v = (mL < 10) ? W1[mL*128 + 64 + kt*32 + k0q + j] : 0.f;
            s[j] = (short)f2bf(v);
        }
        W1sB[kt] = s;
    }
    const float boL = bo[uw + mL];
    float cs2[4] = {0.f,0.f,0.f,0.f};
    __syncthreads();

    // ===================== decoder loop =====================
    for (int ty = 0; ty < TY; ty++){
        {   // sW1 = s @ W1[:,64:].T via MFMA (4 MFMAs, all waves redundantly)
            f4 accW = (f4){0.f,0.f,0.f,0.f};
            #pragma unroll
            for (int kt = 0; kt < 2; kt++){
                const short8 shh = *(const short8*)&sm.u.d.sh[mL][kt*32 + k0q];
                const short8 sll = *(const short8*)&sm.u.d.sl[mL][kt*32 + k0q];
                accW = mfma16(shh, W1sB[kt], accW);
                accW = mfma16(sll, W1sB[kt], accW);
            }
            if (qL < 2 && mL < 10 && wv == 0){
                #pragma unroll
                for (int reg = 0; reg < 4; reg++) sm.u.d.sW1[qL*4+reg][mL] = accW[reg];
            }
        }
        __syncthreads();
        if (tid < 240){                                  // en = relu(tanh(aW1+sW1) . w2 + b2)
            const int er = tid/30, et = tid - er*30;
            float env = sm.u.d.b2s;
            #pragma unroll
            for (int j = 0; j < 10; j++){
                const float z = sm.u.d.aW1[er][et][j] + sm.u.d.sW1[er][j];
                env += sm.u.d.w2b[j]*tanh_(z);
            }
            sm.u.d.en[er][et] = fmaxf(env, 0.f);
        }
        __syncthreads();
        {   // fused softmax+context: single exp pass, normalize at end
            const int cr = tid >> 5, cup = tid & 31;
            const float* enr = sm.u.d.en[cr];
            float mx = enr[0];
            #pragma unroll
            for (int t2 = 1; t2 < TX; t2++) mx = fmaxf(mx, enr[t2]);
            float ssum = 0.f, s0 = 0.f, s1 = 0.f;
            const u16* ap = &sm.a[cr][0][2*cup];
            #pragma unroll 5
            for (int t2 = 0; t2 < TX; t2++){
                const float e = __expf(enr[t2]-mx);
                const u32 pa = *(const u32*)(ap + t2*72);
                ssum += e;
                s0 += e*lo2f(pa); s1 += e*hi2f(pa);
            }
            const float inv = frcp(ssum);
            s0 *= inv; s1 *= inv;
            const u16 h0 = f2bf(s0), h1 = f2bf(s1);
            const u16 l0 = f2bf(s0 - bf2f_u16(h0)), l1 = f2bf(s1 - bf2f_u16(h1));
            *(u32*)&sm.u.d.ctxh[cr][2*cup] = (u32)h0 | ((u32)h1 << 16);
            *(u32*)&sm.u.d.ctxl[cr][2*cup] = (u32)l0 | ((u32)l1 << 16);
        }
        __syncthreads();
        // z2 = [ctx|s] @ Wp^T + bp   (in-register gates)
        f4 acc2[4];
        #pragma unroll
        for (int gt = 0; gt < 4; gt++) acc2[gt] = (f4){pb4[gt],pb4[gt],pb4[gt],pb4[gt]};
        #pragma unroll
        for (int kt = 0; kt < 2; kt++){
            const short8 ch  = *(const short8*)&sm.u.d.ctxh[mL][kt*32 + k0q];
            const short8 cl  = *(const short8*)&sm.u.d.ctxl[mL][kt*32 + k0q];
            const short8 shh = *(const short8*)&sm.u.d.sh[mL][kt*32 + k0q];
            const short8 sll = *(const short8*)&sm.u.d.sl[mL][kt*32 + k0q];
            #pragma unroll
            for (int gt = 0; gt < 4; gt++){
                acc2[gt] = mfma16(ch,  Bip[gt][kt], acc2[gt]);
                acc2[gt] = mfma16(cl,  Bip[gt][kt], acc2[gt]);
                acc2[gt] = mfma16(shh, Bhp[gt][kt], acc2[gt]);
                acc2[gt] = mfma16(sll, Bhp[gt][kt], acc2[gt]);
            }
        }
        __syncthreads();                                 // frag reads done before s overwrite
        if (qL < 2){
            #pragma unroll
            for (int reg = 0; reg < 4; reg++){
                const int m = qL*4 + reg;
                const float ii = sigm(acc2[0][reg]), ff = sigm(acc2[1][reg]);
                const float gg = tanh_(acc2[2][reg]), oo = sigm(acc2[3][reg]);
                cs2[reg] = ff*cs2[reg] + ii*gg;
                const float sv = oo * tanh_(cs2[reg]);
                const u16 shi = f2bf(sv);
                const u16 slo = f2bf(sv - bf2f_u16(shi));
                sm.u.d.sh[m][uw+mL]  = shi;
                sm.u.d.sl[m][uw+mL]  = slo;
            }
        }
        __syncthreads();
        // out = s @ Wo^T + bo
        f4 acc3 = (f4){boL, boL, boL, boL};
        #pragma unroll
        for (int kt = 0; kt < 2; kt++){
            const short8 shh = *(const short8*)&sm.u.d.sh[mL][kt*32 + k0q];
            const short8 sll = *(const short8*)&sm.u.d.sl[mL][kt*32 + k0q];
            acc3 = mfma16(shh, Bo2[kt], acc3);
            acc3 = mfma16(sll, Bo2[kt], acc3);
        }
        if (qL < 2){
            #pragma unroll
            for (int reg = 0; reg < 4; reg++){
                const int m = qL*4 + reg;
                out[(((long)(b0+m))*TY + ty)*64 + uw + mL] = acc3[reg];
            }
        }
    }
}

extern "C" void kernel_launch(void* const* d_in, const int* in_sizes, int n_in,
                              void* d_out, int out_size, void* d_ws, size_t ws_size,
                              hipStream_t stream) {
    const float* X    = (const float*)d_in[0];
    const float* Wihf = (const float*)d_in[1];
    const float* Whhf = (const float*)d_in[2];
    const float* bfv  = (const float*)d_in[3];
    const float* Wihr = (const float*)d_in[4];
    const float* Whhr = (const float*)d_in[5];
    const float* brv  = (const float*)d_in[6];
    const float* W1   = (const float*)d_in[7];
    const float* b1   = (const float*)d_in[8];
    const float* W2   = (const float*)d_in[9];
    const float* b2   = (const float*)d_in[10];
    const float* Wihp = (const float*)d_in[11];
    const float* Whhp = (const float*)d_in[12];
    const float* bp   = (const float*)d_in[13];
    const float* Wo   = (const float*)d_in[14];
    const float* bo   = (const float*)d_in[15];
    float* out = (float*)d_out;

    const int B = in_sizes[0] / (TX * 128);
    dim3 grid(B / BT), block(256);
    hipLaunchKernelGGL(fused_kernel, grid, block, 0, stream,
                       X, Wihf, Whhf, bfv, Wihr, Whhr, brv,
                       W1, b1, W2, b2, Wihp, Whhp, bp, Wo, bo, out);
}